// Round 1
// baseline (730.159 us; speedup 1.0000x reference)
//
#include <hip/hip_runtime.h>
#include <cstdint>
#include <cstddef>

typedef _Float16 half8 __attribute__((ext_vector_type(8)));
typedef _Float16 half4v __attribute__((ext_vector_type(4)));
typedef float f32x4 __attribute__((ext_vector_type(4)));

#define NBATCH 65536
#define NCOL 512   // 2*M interleaved (re,im)
#define KY 256     // 2*N interleaved

// ---------- async global->LDS, 16B per lane ----------
__device__ __forceinline__ void async_copy16(const void* g, void* l) {
  auto gp = reinterpret_cast<__attribute__((address_space(1))) void*>(
      reinterpret_cast<uintptr_t>(g));
  auto lp = reinterpret_cast<__attribute__((address_space(3))) void*>(
      reinterpret_cast<uintptr_t>(l));
  __builtin_amdgcn_global_load_lds(gp, lp, 16, 0, 0);
}

__device__ __forceinline__ float shrinkf(float v, float eta) {
  float a = fabsf(v) - eta;           // LAMBD = 1.0
  return a > 0.0f ? copysignf(a, v) : 0.0f;
}

// ---------- table builders ----------
// Wa[n=2p+c][k=2q+d], 512 x 256: realified A (U = Y @ Wa^T gives Ay interleaved)
__global__ void build_wa(const float* __restrict__ A, _Float16* __restrict__ Wa) {
  int idx = blockIdx.x * 256 + threadIdx.x;     // 131072
  int n = idx >> 8, k = idx & 255;
  int p = n >> 1, c = n & 1, q = k >> 1, d = k & 1;
  const float* A0 = A;                // (256,128)
  const float* A1 = A + 256 * 128;
  float v;
  if (c == 0) v = (d == 0) ? A0[p * 128 + q] : -A1[p * 128 + q];
  else        v = (d == 0) ? A1[p * 128 + q] :  A0[p * 128 + q];
  Wa[idx] = (_Float16)v;
}

// Wc_t = realify(I - g_t * B), 10 tables of 512 x 512
__global__ void build_wc(const float* __restrict__ B, const float* __restrict__ gammas,
                         _Float16* __restrict__ Wc) {
  int idx = blockIdx.x * 256 + threadIdx.x;     // 2,621,440
  int t = idx >> 18;
  int r = idx & 262143;
  int n = r >> 9, k = r & 511;
  int p = n >> 1, c = n & 1, q = k >> 1, d = k & 1;
  float g = gammas[t + 1];
  const float* B0 = B;                // (256,256)
  const float* B1 = B + 256 * 256;
  float eye = (p == q) ? 1.0f : 0.0f;
  float v;
  if (c == 0) v = (d == 0) ? (eye - g * B0[p * 256 + q]) : ( g * B1[p * 256 + q]);
  else        v = (d == 0) ? (     - g * B1[p * 256 + q]) : (eye - g * B0[p * 256 + q]);
  Wc[idx] = (_Float16)v;
}

// y fp32 -> fp16 (layout already (b, 2q+d))
__global__ void convert_y(const float* __restrict__ y, _Float16* __restrict__ y16) {
  size_t i = (size_t)(blockIdx.x * 256 + threadIdx.x) * 4;
  float4 v = *(const float4*)(y + i);
  half4v h = {(_Float16)v.x, (_Float16)v.y, (_Float16)v.z, (_Float16)v.w};
  *(half4v*)(y16 + i) = h;
}

// final X fp16 -> d_out fp32 (only used when Ay lives inside d_out)
__global__ void convert_out(const _Float16* __restrict__ x, float* __restrict__ out) {
  size_t i = (size_t)(blockIdx.x * 256 + threadIdx.x) * 4;
  half4v h = *(const half4v*)(x + i);
  f32x4 o = {(float)h.x, (float)h.y, (float)h.z, (float)h.w};
  *(f32x4*)(out + i) = o;
}

// ---------- main GEMM step ----------
// 128x128 tile, BK=64, 4 waves of 4x4 16x16x32_f16 frags.
// MODE 0: write ayOut = acc (raw), outH = shrink(g*acc, eta)           (K-tiles = 4)
// MODE 1: outH = shrink(acc + g*Ay, eta)  fp16                          (K-tiles = 8)
// MODE 2: outF = shrink(acc + g*Ay, eta)  fp32 to d_out                 (K-tiles = 8)
template <int KT, int MODE>
__global__ __launch_bounds__(256, 2) void gemm_step(
    const _Float16* __restrict__ Asrc, int lda,
    const _Float16* __restrict__ Bsrc, int ldb,
    const _Float16* __restrict__ Ay,
    _Float16* __restrict__ outH,
    _Float16* __restrict__ ayOut,
    float* __restrict__ outF,
    const float* __restrict__ gammas, const float* __restrict__ etas, int gt) {
  __shared__ _Float16 sA[2][128 * 64];
  __shared__ _Float16 sB[2][128 * 64];

  // XCD swizzle: the 4 col-blocks of a row-block land 8 apart -> same XCD L2
  const int bid = blockIdx.x;
  const int grp = bid >> 5, sub = bid & 31;
  const int colb = sub >> 3;
  const int rowb = grp * 8 + (sub & 7);
  const int m0 = rowb * 128;
  const int n0 = colb * 128;

  const int tid = threadIdx.x;
  const int lane = tid & 63;
  const int wave = tid >> 6;
  const int wr = wave >> 1, wc = wave & 1;
  const int quad = lane >> 4, l16 = lane & 15;

  f32x4 acc[4][4];
#pragma unroll
  for (int i = 0; i < 4; ++i)
#pragma unroll
    for (int j = 0; j < 4; ++j) acc[i][j] = {0.f, 0.f, 0.f, 0.f};

  auto stage = [&](int kt, int buf) {
    const int k0 = kt * 64;
#pragma unroll
    for (int i = 0; i < 4; ++i) {
      const int c = i * 256 + tid;
      const int row = c >> 3, pos = c & 7;
      const int col8 = pos ^ (row & 7);   // XOR chunk swizzle (bank-conflict-free frags)
      async_copy16(Asrc + (size_t)(m0 + row) * lda + (size_t)(k0 + col8 * 8),
                   &sA[buf][(size_t)(i * 256 + (tid & ~63)) * 8]);
      async_copy16(Bsrc + (size_t)(n0 + row) * ldb + (size_t)(k0 + col8 * 8),
                   &sB[buf][(size_t)(i * 256 + (tid & ~63)) * 8]);
    }
  };

  stage(0, 0);
  for (int kt = 0; kt < KT; ++kt) {
    __syncthreads();  // drains vmcnt: buf[kt&1] staged; prior reads of other buf done
    if (kt + 1 < KT) stage(kt + 1, (kt + 1) & 1);
    const _Float16* bufA = sA[kt & 1];
    const _Float16* bufB = sB[kt & 1];
#pragma unroll
    for (int ks = 0; ks < 2; ++ks) {
      half8 af[4], bf[4];
#pragma unroll
      for (int i = 0; i < 4; ++i) {
        const int r = wr * 64 + i * 16 + l16;
        const int cp = (ks * 4 + quad) ^ (r & 7);
        af[i] = *(const half8*)(bufA + r * 64 + cp * 8);
        const int rb = wc * 64 + i * 16 + l16;
        const int cpb = (ks * 4 + quad) ^ (rb & 7);
        bf[i] = *(const half8*)(bufB + rb * 64 + cpb * 8);
      }
#pragma unroll
      for (int i = 0; i < 4; ++i)
#pragma unroll
        for (int j = 0; j < 4; ++j)
          acc[i][j] = __builtin_amdgcn_mfma_f32_16x16x32_f16(af[i], bf[j], acc[i][j], 0, 0, 0);
    }
  }

  const float g = gammas[gt];
  const float eta = etas[gt];
#pragma unroll
  for (int i = 0; i < 4; ++i) {
#pragma unroll
    for (int j = 0; j < 4; ++j) {
      const int gr0 = m0 + wr * 64 + i * 16 + quad * 4;  // C/D: row=(lane>>4)*4+reg
      const int gc = n0 + wc * 64 + j * 16 + l16;        //      col=lane&15
#pragma unroll
      for (int r = 0; r < 4; ++r) {
        const size_t off = (size_t)(gr0 + r) * NCOL + gc;
        const float v = acc[i][j][r];
        if (MODE == 0) {
          ayOut[off] = (_Float16)v;
          outH[off] = (_Float16)shrinkf(g * v, eta);
        } else if (MODE == 1) {
          outH[off] = (_Float16)shrinkf(v + g * (float)Ay[off], eta);
        } else {
          outF[off] = shrinkf(v + g * (float)Ay[off], eta);
        }
      }
    }
  }
}

extern "C" void kernel_launch(void* const* d_in, const int* in_sizes, int n_in,
                              void* d_out, int out_size, void* d_ws, size_t ws_size,
                              hipStream_t stream) {
  const float* y      = (const float*)d_in[0];
  const float* A      = (const float*)d_in[1];
  const float* B      = (const float*)d_in[2];
  const float* etas   = (const float*)d_in[3];
  const float* gammas = (const float*)d_in[4];

  char* ws = (char*)d_ws;
  size_t off = 0;
  auto take = [&](size_t bytes) { char* p = ws + off; off += bytes; return p; };

  _Float16* Wa = (_Float16*)take(262144);       // 512*256*2
  _Float16* Wc = (_Float16*)take(5242880);      // 10*512*512*2
  _Float16* xA = (_Float16*)take(67108864);     // 65536*512*2
  _Float16* xB = (_Float16*)take(67108864);

  const bool full = ws_size >= 240386048ull;    // + Y16 + Ay in ws
  _Float16* Y16;
  _Float16* Ay;
  if (full) {
    Y16 = (_Float16*)take(33554432);
    Ay  = (_Float16*)take(67108864);
  } else {
    // use d_out as scratch for Y16 (32MB) + Ay (64MB); final convert rewrites d_out
    Y16 = (_Float16*)d_out;
    Ay  = (_Float16*)((char*)d_out + 33554432);
  }

  hipLaunchKernelGGL(build_wa, dim3(512), dim3(256), 0, stream, A, Wa);
  hipLaunchKernelGGL(build_wc, dim3(10240), dim3(256), 0, stream, B, gammas, Wc);
  hipLaunchKernelGGL(convert_y, dim3(16384), dim3(256), 0, stream, y, Y16);

  // Ay = Y @ Wa^T ; x0 = shrink(g0 * Ay, eta0)
  hipLaunchKernelGGL((gemm_step<4, 0>), dim3(2048), dim3(256), 0, stream,
                     Y16, KY, Wa, KY, (const _Float16*)nullptr,
                     xA, Ay, (float*)nullptr, gammas, etas, 0);

  _Float16* cur = xA;
  _Float16* nxt = xB;
  for (int t = 1; t <= 10; ++t) {
    const _Float16* Wt = Wc + (size_t)(t - 1) * 262144;  // elements
    if (t < 10) {
      hipLaunchKernelGGL((gemm_step<8, 1>), dim3(2048), dim3(256), 0, stream,
                         cur, NCOL, Wt, NCOL, Ay,
                         nxt, (_Float16*)nullptr, (float*)nullptr, gammas, etas, t);
      _Float16* tmp = cur; cur = nxt; nxt = tmp;
    } else if (full) {
      hipLaunchKernelGGL((gemm_step<8, 2>), dim3(2048), dim3(256), 0, stream,
                         cur, NCOL, Wt, NCOL, Ay,
                         (_Float16*)nullptr, (_Float16*)nullptr, (float*)d_out,
                         gammas, etas, t);
    } else {
      hipLaunchKernelGGL((gemm_step<8, 1>), dim3(2048), dim3(256), 0, stream,
                         cur, NCOL, Wt, NCOL, Ay,
                         nxt, (_Float16*)nullptr, (float*)nullptr, gammas, etas, t);
      hipLaunchKernelGGL(convert_out, dim3(32768), dim3(256), 0, stream,
                         nxt, (float*)d_out);
    }
  }
}